// Round 1
// baseline (897.873 us; speedup 1.0000x reference)
//
#include <hip/hip_runtime.h>
#include <hip/hip_bf16.h>
#include <cstdint>

// Problem: B=8, C=256, N=64*64=4096 self-attention over spatial tokens.
//   q,k,v = per-pixel linear maps (1x1 conv); energy = q^T k per batch [N,N];
//   softmax over keys; out = V @ P^T; y = gamma*out + x.
// Strategy: flash-style online softmax (never materialize [N,N]),
//   bf16 MFMA 16x16x32 for QK^T and PV.  Workspace: Qc[C][N], Kr[N][C],
//   Vc[C][N] per batch, bf16 (3 x 16 MB = 48 MB + change).

typedef short short8 __attribute__((ext_vector_type(8)));
typedef float f32x4 __attribute__((ext_vector_type(4)));

#define MFMA16(a, b, c) __builtin_amdgcn_mfma_f32_16x16x32_bf16((a), (b), (c), 0, 0, 0)

__device__ __forceinline__ unsigned short f2bf(float f) {
    union { float f; unsigned int u; } v;
    v.f = f;
    unsigned int u = v.u;
    return (unsigned short)((u + 0x7fffu + ((u >> 16) & 1u)) >> 16);
}

// ---------------- Kernel 1: QKV projection (fp32 math, bf16 out) -------------
// Qc: [B][C][N]   Kr: [B][N][C]   Vc: [B][C][N]
__global__ __launch_bounds__(256) void qkv_kernel(
    const float* __restrict__ x,
    const float* __restrict__ wq, const float* __restrict__ bq,
    const float* __restrict__ wk, const float* __restrict__ bk,
    const float* __restrict__ wv, const float* __restrict__ bv,
    unsigned short* __restrict__ Qc, unsigned short* __restrict__ Kr,
    unsigned short* __restrict__ Vc)
{
    const int C = 256, N = 4096;
    const int b  = blockIdx.z;
    const int o0 = blockIdx.y * 8;
    const int n  = blockIdx.x * 256 + threadIdx.x;

    float aq[8], ak[8], av[8];
#pragma unroll
    for (int i = 0; i < 8; i++) {
        aq[i] = bq[o0 + i];
        ak[i] = bk[o0 + i];
        av[i] = bv[o0 + i];
    }
    const float* xb = x + ((size_t)b * C) * N + n;
#pragma unroll 4
    for (int c = 0; c < C; c++) {
        float xv = xb[(size_t)c * N];
#pragma unroll
        for (int i = 0; i < 8; i++) {
            aq[i] = fmaf(wq[(o0 + i) * C + c], xv, aq[i]);
            ak[i] = fmaf(wk[(o0 + i) * C + c], xv, ak[i]);
            av[i] = fmaf(wv[(o0 + i) * C + c], xv, av[i]);
        }
    }
#pragma unroll
    for (int i = 0; i < 8; i++) {
        int o = o0 + i;
        Qc[((size_t)(b * C + o)) * N + n] = f2bf(aq[i]);
        Vc[((size_t)(b * C + o)) * N + n] = f2bf(av[i]);
        Kr[((size_t)(b * N + n)) * C + o] = f2bf(ak[i]);
    }
}

// ---------------- Kernel 2: flash attention + epilogue -----------------------
// Grid (N/64, B), block 256 = 4 waves.  Each wave: 16 queries x full C=256.
// MFMA fragment layouts (gfx950, verified):
//   A[m = lane&15][k = (lane>>4)*8 + j]
//   B[n = lane&15][k = (lane>>4)*8 + j]
//   C/D[row = (lane>>4)*4 + r][col = lane&15]
__global__ __launch_bounds__(256) void attn_kernel(
    const unsigned short* __restrict__ Qc,
    const unsigned short* __restrict__ Kr,
    const unsigned short* __restrict__ Vc,
    const float* __restrict__ x,
    const float* __restrict__ gamma,
    float* __restrict__ out)
{
    const int C = 256, N = 4096, KT = 32;
    __shared__ __align__(16) unsigned short Kt[32 * 264];     // [key][c], pad->264
    __shared__ __align__(16) unsigned short Pt[4][16 * 40];   // per-wave P relayout

    const int tid  = threadIdx.x;
    const int wave = tid >> 6;
    const int lane = tid & 63;
    const int quad = lane >> 4;
    const int l16  = lane & 15;
    const int b    = blockIdx.y;
    const int q0   = blockIdx.x * 64 + wave * 16;

    // Q A-fragments: 8 frags cover K-dim C=256 (held in regs whole kernel)
    short8 aq[8];
    {
        const unsigned short* qb = Qc + ((size_t)b * C) * N + q0 + l16;
#pragma unroll
        for (int f = 0; f < 8; f++) {
#pragma unroll
            for (int j = 0; j < 8; j++) {
                int c = f * 32 + quad * 8 + j;
                aq[f][j] = (short)qb[(size_t)c * N];
            }
        }
    }

    f32x4 o_acc[16];
#pragma unroll
    for (int t = 0; t < 16; t++) o_acc[t] = (f32x4){0.f, 0.f, 0.f, 0.f};
    float m_r[4], l_r[4];
#pragma unroll
    for (int r = 0; r < 4; r++) { m_r[r] = -__builtin_inff(); l_r[r] = 0.f; }

    const unsigned short* kb = Kr + ((size_t)b * N) * C;
    const unsigned short* vb = Vc + ((size_t)(b * C + l16)) * N + quad * 8;

    for (int m0 = 0; m0 < N; m0 += KT) {
        // ---- stage K tile: global [key][c] -> LDS [key][264] (b128 both ways)
#pragma unroll
        for (int p = 0; p < 4; p++) {
            int idx = p * 256 + tid;
            int key = idx >> 5;
            int c8  = (idx & 31) * 8;
            short8 kv = *(const short8*)(kb + (size_t)(m0 + key) * C + c8);
            *(short8*)(&Kt[key * 264 + c8]) = kv;
        }
        __syncthreads();

        // ---- S = Q K^T : 16 queries x 32 keys
        f32x4 s0 = (f32x4){0.f, 0.f, 0.f, 0.f};
        f32x4 s1 = (f32x4){0.f, 0.f, 0.f, 0.f};
#pragma unroll
        for (int f = 0; f < 8; f++) {
            int cbase = f * 32 + quad * 8;
            short8 b0 = *(const short8*)(&Kt[l16 * 264 + cbase]);
            short8 b1 = *(const short8*)(&Kt[(l16 + 16) * 264 + cbase]);
            s0 = MFMA16(aq[f], b0, s0);
            s1 = MFMA16(aq[f], b1, s1);
        }

        // ---- online softmax (row = query = quad*4+r, 16-lane reductions)
        float alpha[4];
#pragma unroll
        for (int r = 0; r < 4; r++) {
            float mx = fmaxf(s0[r], s1[r]);
            mx = fmaxf(mx, __shfl_xor(mx, 1));
            mx = fmaxf(mx, __shfl_xor(mx, 2));
            mx = fmaxf(mx, __shfl_xor(mx, 4));
            mx = fmaxf(mx, __shfl_xor(mx, 8));
            float mn = fmaxf(m_r[r], mx);
            float al = __expf(m_r[r] - mn);
            m_r[r] = mn;
            float e0 = __expf(s0[r] - mn);
            float e1 = __expf(s1[r] - mn);
            float rs = e0 + e1;
            rs += __shfl_xor(rs, 1);
            rs += __shfl_xor(rs, 2);
            rs += __shfl_xor(rs, 4);
            rs += __shfl_xor(rs, 8);
            l_r[r] = l_r[r] * al + rs;
            alpha[r] = al;
            Pt[wave][(quad * 4 + r) * 40 + l16]      = f2bf(e0);
            Pt[wave][(quad * 4 + r) * 40 + 16 + l16] = f2bf(e1);
        }
        // rescale accumulators by alpha (per row)
#pragma unroll
        for (int t = 0; t < 16; t++) {
#pragma unroll
            for (int r = 0; r < 4; r++) o_acc[t][r] *= alpha[r];
        }

        // ---- P -> A-layout via per-wave LDS round-trip, then PV
        short8 ap = *(const short8*)(&Pt[wave][l16 * 40 + quad * 8]);
#pragma unroll
        for (int t = 0; t < 16; t++) {
            short8 bv = *(const short8*)(vb + (size_t)t * 16 * N + m0);
            o_acc[t] = MFMA16(ap, bv, o_acc[t]);
        }
        __syncthreads();
    }

    // ---- epilogue: y = gamma * (O / l) + x
    const float g = gamma[0];
    float inv[4];
#pragma unroll
    for (int r = 0; r < 4; r++) inv[r] = g / l_r[r];
#pragma unroll
    for (int t = 0; t < 16; t++) {
#pragma unroll
        for (int r = 0; r < 4; r++) {
            int c = t * 16 + l16;
            int n = q0 + quad * 4 + r;
            size_t idx = ((size_t)(b * C + c)) * N + n;
            out[idx] = fmaf(o_acc[t][r], inv[r], x[idx]);
        }
    }
}

extern "C" void kernel_launch(void* const* d_in, const int* in_sizes, int n_in,
                              void* d_out, int out_size, void* d_ws, size_t ws_size,
                              hipStream_t stream) {
    const int B = 8, C = 256, N = 4096;
    const float* x     = (const float*)d_in[0];
    const float* wq    = (const float*)d_in[1];
    const float* bq    = (const float*)d_in[2];
    const float* wk    = (const float*)d_in[3];
    const float* bk    = (const float*)d_in[4];
    const float* wv    = (const float*)d_in[5];
    const float* bv    = (const float*)d_in[6];
    const float* gamma = (const float*)d_in[7];
    float* out = (float*)d_out;

    unsigned short* Qc = (unsigned short*)d_ws;             // [B][C][N] bf16
    unsigned short* Kr = Qc + (size_t)B * C * N;            // [B][N][C] bf16
    unsigned short* Vc = Kr + (size_t)B * C * N;            // [B][C][N] bf16

    qkv_kernel<<<dim3(N / 256, C / 8, B), 256, 0, stream>>>(
        x, wq, bq, wk, bk, wv, bv, Qc, Kr, Vc);
    attn_kernel<<<dim3(N / 64, B), 256, 0, stream>>>(Qc, Kr, Vc, x, gamma, out);
}